// Round 4
// baseline (172.316 us; speedup 1.0000x reference)
//
#include <hip/hip_runtime.h>
#include <math.h>

// WL1 loss over [B=16, C=3, H=512, W=512] fp32.
//   r = sum_c|hr-sr|/255 ; e = sum_c|hr-ema|/255
//   patch_w[b] = (unbiased var of r over sample)^0.2
//   pixel_w = unbiased 3x3 local var of r (reflect pad)
//   loss = mean(|w*sr - w*hr|) = (1/N) sum patch_w * pixel_w * mask * 255*r
//
// R5: barrier-free rolling-window kernel. Evidence from R1-R4: the LDS+barrier
// phase structure blocks software pipelining (compiler won't keep loads in
// flight across __syncthreads; VGPR collapsed to 36 even with a 128 budget)
// and the bottleneck is loads-in-flight, not occupancy. New structure: each
// wave owns an 8-row x 256-col strip, walks rows with a 3-row rolling register
// window. Horizontal 3x3 halo via __shfl_up/down inside the wave; strip-edge
// columns via 2-lane predicated scalar loads. Explicit 1-row prefetch (loads
// for row st+1 issued into named regs before row st's compute) keeps ~9
// float4 loads continuously outstanding per wave. No LDS tile, no barriers in
// the loop. All register indices static (full unroll).

#define BB 16
#define HH 512
#define WW 512
#define HW (HH * WW)
#define CHW (3 * HW)
#define SH 8
#define STRIPS (HH / SH)                   // 64
#define BLOCKS_PER_BATCH ((STRIPS * 2) / 4)  // 32 (4 waves/block)
#define NBLOCKS (BB * BLOCKS_PER_BATCH)    // 512

__device__ __forceinline__ int reflect_h(int gh) {
  gh = gh < 0 ? -gh : gh;
  return gh >= HH ? 2 * HH - 2 - gh : gh;
}

struct Row {
  float4 h0, h1, h2, s0, s1, s2, m0, m1, m2;
  float eh0, eh1, eh2, es0, es1, es2;
};

__device__ __forceinline__ Row load_row(const float* __restrict__ hrb,
                                        const float* __restrict__ srb,
                                        const float* __restrict__ emb,
                                        int gh, int col, bool isEdge, int gwE,
                                        bool with_e) {
  Row r;
  const int base = gh * WW + col;
  r.h0 = *(const float4*)(hrb + base);
  r.h1 = *(const float4*)(hrb + base + HW);
  r.h2 = *(const float4*)(hrb + base + 2 * HW);
  r.s0 = *(const float4*)(srb + base);
  r.s1 = *(const float4*)(srb + base + HW);
  r.s2 = *(const float4*)(srb + base + 2 * HW);
  if (with_e) {
    r.m0 = *(const float4*)(emb + base);
    r.m1 = *(const float4*)(emb + base + HW);
    r.m2 = *(const float4*)(emb + base + 2 * HW);
  }
  if (isEdge) {
    const int be = gh * WW + gwE;
    r.eh0 = hrb[be];
    r.eh1 = hrb[be + HW];
    r.eh2 = hrb[be + 2 * HW];
    r.es0 = srb[be];
    r.es1 = srb[be + HW];
    r.es2 = srb[be + 2 * HW];
  }
  return r;
}

__global__ __launch_bounds__(256, 2) void wl1_main(
    const float* __restrict__ sr, const float* __restrict__ srema,
    const float* __restrict__ hr,
    float* __restrict__ p_sum, float* __restrict__ p_sum2,
    float* __restrict__ p_loss) {
  const int tid = threadIdx.x;
  const int wv = tid >> 6;
  const int lane = tid & 63;
  const int bid = blockIdx.x;
  const int b = bid >> 5;                   // 32 blocks per batch
  const int slot = ((bid & 31) << 2) | wv;  // 0..127: 64 strips x 2 w-tiles
  const int r0 = (slot >> 1) * SH;
  const int w0 = (slot & 1) << 8;  // 0 or 256
  const int col = w0 + 4 * lane;
  const bool isEdge = (lane == 0) || (lane == 63);
  // edge column this lane is responsible for (lane0: left of tile, lane63:
  // right of tile), with reflect at image borders
  const int gwE = (lane == 0) ? (w0 ? w0 - 1 : 1)
                              : (w0 + 256 < WW ? w0 + 256 : 2 * WW - 2 - (w0 + 256));
  const float* __restrict__ srb = sr + (size_t)b * CHW;
  const float* __restrict__ hrb = hr + (size_t)b * CHW;
  const float* __restrict__ emb = srema + (size_t)b * CHW;

  // rolling state: horizontal 3-col sums (h*) and sum-squares (q*) for the
  // two previous rows; center r and e of the previous row.
  float hA[4] = {0, 0, 0, 0}, qA[4] = {0, 0, 0, 0};
  float hB[4] = {0, 0, 0, 0}, qB[4] = {0, 0, 0, 0};
  float cB[4] = {0, 0, 0, 0}, eB[4] = {0, 0, 0, 0};
  float v1 = 0.f, v2 = 0.f, v3 = 0.f;

  Row cur = load_row(hrb, srb, emb, reflect_h(r0 - 1), col, isEdge, gwE, false);
#pragma unroll
  for (int st = 0; st <= SH + 1; ++st) {
    // ---- prefetch next input row (ri_next = r0 + st) ----
    Row nxt;
    if (st <= SH) {
      const int gh1 = (st == SH) ? reflect_h(r0 + SH) : (r0 + st);
      nxt = load_row(hrb, srb, emb, gh1, col, isEdge, gwE, st < SH);
    }
    // ---- compute current input row (ri = r0 - 1 + st) ----
    float4 r4;
    r4.x = (fabsf(cur.h0.x - cur.s0.x) + fabsf(cur.h1.x - cur.s1.x) +
            fabsf(cur.h2.x - cur.s2.x)) / 255.0f;
    r4.y = (fabsf(cur.h0.y - cur.s0.y) + fabsf(cur.h1.y - cur.s1.y) +
            fabsf(cur.h2.y - cur.s2.y)) / 255.0f;
    r4.z = (fabsf(cur.h0.z - cur.s0.z) + fabsf(cur.h1.z - cur.s1.z) +
            fabsf(cur.h2.z - cur.s2.z)) / 255.0f;
    r4.w = (fabsf(cur.h0.w - cur.s0.w) + fabsf(cur.h1.w - cur.s1.w) +
            fabsf(cur.h2.w - cur.s2.w)) / 255.0f;
    float redge = 0.f;
    if (isEdge)
      redge = (fabsf(cur.eh0 - cur.es0) + fabsf(cur.eh1 - cur.es1) +
               fabsf(cur.eh2 - cur.es2)) / 255.0f;
    const float fl = __shfl_up(r4.w, 1, 64);
    const float fr = __shfl_down(r4.x, 1, 64);
    const float f3 = (lane == 0) ? redge : fl;
    const float f8 = (lane == 63) ? redge : fr;
    const float f0 = f3, f1v = r4.x, f2v = r4.y, f3v = r4.z, f4v = r4.w, f5v = f8;
    float hC[4], qC[4];
    hC[0] = f0 + f1v + f2v;
    hC[1] = f1v + f2v + f3v;
    hC[2] = f2v + f3v + f4v;
    hC[3] = f3v + f4v + f5v;
    qC[0] = f0 * f0 + f1v * f1v + f2v * f2v;
    qC[1] = f1v * f1v + f2v * f2v + f3v * f3v;
    qC[2] = f2v * f2v + f3v * f3v + f4v * f4v;
    qC[3] = f3v * f3v + f4v * f4v + f5v * f5v;
    float e4[4] = {0, 0, 0, 0};
    if (st >= 1 && st <= SH) {  // ri is an output row: compute e
      e4[0] = (fabsf(cur.h0.x - cur.m0.x) + fabsf(cur.h1.x - cur.m1.x) +
               fabsf(cur.h2.x - cur.m2.x)) / 255.0f;
      e4[1] = (fabsf(cur.h0.y - cur.m0.y) + fabsf(cur.h1.y - cur.m1.y) +
               fabsf(cur.h2.y - cur.m2.y)) / 255.0f;
      e4[2] = (fabsf(cur.h0.z - cur.m0.z) + fabsf(cur.h1.z - cur.m1.z) +
               fabsf(cur.h2.z - cur.m2.z)) / 255.0f;
      e4[3] = (fabsf(cur.h0.w - cur.m0.w) + fabsf(cur.h1.w - cur.m1.w) +
               fabsf(cur.h2.w - cur.m2.w)) / 255.0f;
    }
    // ---- emit output row o = ri - 1 (needs rows o-1=A, o=B, o+1=C) ----
    if (st >= 2) {
#pragma unroll
      for (int cc = 0; cc < 4; ++cc) {
        const float s3 = hA[cc] + hB[cc] + hC[cc];
        const float q3 = qA[cc] + qB[cc] + qC[cc];
        const float pvar = (q3 - s3 * s3 / 9.0f) / 8.0f;
        const float rc = cB[cc];
        v1 += rc;
        v2 += rc * rc;
        if (rc >= eB[cc]) v3 += pvar * (255.0f * rc);
      }
    }
    // ---- rotate ----
#pragma unroll
    for (int cc = 0; cc < 4; ++cc) {
      hA[cc] = hB[cc];
      qA[cc] = qB[cc];
      hB[cc] = hC[cc];
      qB[cc] = qC[cc];
    }
    cB[0] = r4.x; cB[1] = r4.y; cB[2] = r4.z; cB[3] = r4.w;
    eB[0] = e4[0]; eB[1] = e4[1]; eB[2] = e4[2]; eB[3] = e4[3];
    cur = nxt;
  }

  // wave reduce
#pragma unroll
  for (int off = 32; off > 0; off >>= 1) {
    v1 += __shfl_down(v1, off, 64);
    v2 += __shfl_down(v2, off, 64);
    v3 += __shfl_down(v3, off, 64);
  }
  __shared__ float red[3][4];
  if (lane == 0) {
    red[0][wv] = v1;
    red[1][wv] = v2;
    red[2][wv] = v3;
  }
  __syncthreads();
  if (tid == 0) {
    p_sum[bid] = red[0][0] + red[0][1] + red[0][2] + red[0][3];
    p_sum2[bid] = red[1][0] + red[1][1] + red[1][2] + red[1][3];
    p_loss[bid] = red[2][0] + red[2][1] + red[2][2] + red[2][3];
  }
}

// Single fused reduction: wave w handles batch w (32 partials each).
__global__ __launch_bounds__(1024) void wl1_reduce(
    const float* __restrict__ p_sum, const float* __restrict__ p_sum2,
    const float* __restrict__ p_loss, float* __restrict__ out) {
  const int tid = threadIdx.x;
  const int b = tid >> 6, k = tid & 63;
  double s = 0.0, s2 = 0.0, sl = 0.0;
  if (k < BLOCKS_PER_BATCH) {
    const int i = b * BLOCKS_PER_BATCH + k;
    s = (double)p_sum[i];
    s2 = (double)p_sum2[i];
    sl = (double)p_loss[i];
  }
#pragma unroll
  for (int off = 32; off > 0; off >>= 1) {
    s += __shfl_down(s, off, 64);
    s2 += __shfl_down(s2, off, 64);
    sl += __shfl_down(sl, off, 64);
  }
  __shared__ double acc[BB];
  if (k == 0) {
    const double n = (double)HW;
    double var = (s2 - s * s / n) / (n - 1.0);
    acc[b] = pow(var, 0.2) * sl;
  }
  __syncthreads();
  if (tid == 0) {
    double tot = 0.0;
#pragma unroll
    for (int j = 0; j < BB; ++j) tot += acc[j];
    out[0] = (float)(tot / (double)((size_t)BB * CHW));
  }
}

extern "C" void kernel_launch(void* const* d_in, const int* in_sizes, int n_in,
                              void* d_out, int out_size, void* d_ws,
                              size_t ws_size, hipStream_t stream) {
  const float* sr = (const float*)d_in[0];
  const float* srema = (const float*)d_in[1];
  const float* hr = (const float*)d_in[2];
  float* out = (float*)d_out;

  float* p_sum = (float*)d_ws;
  float* p_sum2 = p_sum + NBLOCKS;
  float* p_loss = p_sum2 + NBLOCKS;

  wl1_main<<<NBLOCKS, 256, 0, stream>>>(sr, srema, hr, p_sum, p_sum2, p_loss);
  wl1_reduce<<<1, 1024, 0, stream>>>(p_sum, p_sum2, p_loss, out);
}

// Round 5
// 159.483 us; speedup vs baseline: 1.0805x; 1.0805x over previous
//
#include <hip/hip_runtime.h>
#include <math.h>

// WL1 loss over [B=16, C=3, H=512, W=512] fp32.
//   r = sum_c|hr-sr|/255 ; e = sum_c|hr-ema|/255
//   patch_w[b] = (unbiased var of r over sample)^0.2
//   pixel_w = unbiased 3x3 local var of r (reflect pad)
//   loss = mean(|w*sr - w*hr|) = (1/N) sum patch_w * pixel_w * mask * 255*r
//
// R6: R1's exact code shape (proven fastest: wave-uniform rs, LDS r-tile,
// stage-B hr+ema reload hitting L2) with ONE variable changed: tile height
// 16 -> 8, grid 1024 -> 2048 blocks = 8 blocks/CU = 32 waves/CU. R5 proved
// per-wave MLP is compiler-capped (loads serialize at ~1 outstanding/wave),
// so throughput scales with resident waves. R1 was grid-limited (4 blocks/CU
// while LDS/VGPR allowed 8). No launch_bounds min-waves arg (R2 showed it
// collapses VGPR allocation); R1 shape = 48 VGPR <= 64 so 8 waves/SIMD fits.

#define BB 16
#define HH 512
#define WW 512
#define HW (HH * WW)
#define CHW (3 * HW)
#define TILE_H 8
#define TILES_PER_BATCH 128  // 64 (h strips) x 2 (w halves)
#define NBLOCKS (BB * TILES_PER_BATCH)  // 2048
#define LDS_STRIDE 264  // col 3 = left halo, 4..259 = centers, 260 = right halo

__device__ __forceinline__ int reflect_h(int gh) {
  gh = gh < 0 ? -gh : gh;
  return gh >= HH ? 2 * HH - 2 - gh : gh;
}

__global__ __launch_bounds__(256) void wl1_main(
    const float* __restrict__ sr, const float* __restrict__ srema,
    const float* __restrict__ hr,
    float* __restrict__ p_sum, float* __restrict__ p_sum2,
    float* __restrict__ p_loss) {
  __shared__ float rt[TILE_H + 2][LDS_STRIDE];
  const int bid = blockIdx.x;
  const int b = bid >> 7;
  const int t = bid & 127;
  const int h0 = (t >> 1) << 3;  // 0,8,...,504
  const int w0 = (t & 1) << 8;   // 0 or 256
  const int tid = threadIdx.x;
  const int c4 = tid & 63;       // float4 column group (0..63)
  const int rs = tid >> 6;       // row-sub (0..3) == wave id -> uniform branches
  const float* __restrict__ srb = sr + (size_t)b * CHW;
  const float* __restrict__ hrb = hr + (size_t)b * CHW;
  const float* __restrict__ eb = srema + (size_t)b * CHW;

  // Stage A: halo rows 0..9 of r -> LDS, float4 per lane (rows 4*it+rs)
#pragma unroll
  for (int it = 0; it < 3; ++it) {
    int row = it * 4 + rs;
    if (row < TILE_H + 2) {
      int gh = reflect_h(h0 - 1 + row);
      const float* hb = hrb + gh * WW + w0 + 4 * c4;
      const float* sb = srb + gh * WW + w0 + 4 * c4;
      float4 ha = *(const float4*)(hb);
      float4 hbv = *(const float4*)(hb + HW);
      float4 hc = *(const float4*)(hb + 2 * HW);
      float4 sa = *(const float4*)(sb);
      float4 sbv = *(const float4*)(sb + HW);
      float4 sc = *(const float4*)(sb + 2 * HW);
      float4 r4;
      r4.x = (fabsf(ha.x - sa.x) + fabsf(hbv.x - sbv.x) + fabsf(hc.x - sc.x)) / 255.0f;
      r4.y = (fabsf(ha.y - sa.y) + fabsf(hbv.y - sbv.y) + fabsf(hc.y - sc.y)) / 255.0f;
      r4.z = (fabsf(ha.z - sa.z) + fabsf(hbv.z - sbv.z) + fabsf(hc.z - sc.z)) / 255.0f;
      r4.w = (fabsf(ha.w - sa.w) + fabsf(hbv.w - sbv.w) + fabsf(hc.w - sc.w)) / 255.0f;
      *(float4*)&rt[row][4 + 4 * c4] = r4;
    }
  }
  // Stage A2: left/right halo columns (20 scalar items)
  if (tid < 2 * (TILE_H + 2)) {
    int row = tid >> 1, side = tid & 1;
    int gh = reflect_h(h0 - 1 + row);
    int gw = side ? w0 + 256 : w0 - 1;
    if (gw < 0) gw = 1;
    if (gw > 511) gw = 1022 - gw;
    int base = gh * WW + gw;
    float v = (fabsf(hrb[base] - srb[base]) +
               fabsf(hrb[base + HW] - srb[base + HW]) +
               fabsf(hrb[base + 2 * HW] - srb[base + 2 * HW])) /
              255.0f;
    rt[row][side ? 260 : 3] = v;
  }
  __syncthreads();

  // Stage B: each thread -> 2 rows x 4 cols of outputs (o = 4*rr + rs)
  float v1 = 0.f, v2 = 0.f, v3 = 0.f;
#pragma unroll
  for (int rr = 0; rr < 2; ++rr) {
    const int o = rr * 4 + rs;  // output row within tile, LDS center row = o+1
    float cs[6] = {0, 0, 0, 0, 0, 0}, cq[6] = {0, 0, 0, 0, 0, 0};
    float center[4];
#pragma unroll
    for (int dr = 0; dr < 3; ++dr) {
      const float* lp = &rt[o + dr][4 * c4];
      float4 a = *(const float4*)(lp);
      float4 bq = *(const float4*)(lp + 4);
      float4 cq4 = *(const float4*)(lp + 8);
      float f3 = a.w, f4 = bq.x, f5 = bq.y, f6 = bq.z, f7 = bq.w, f8 = cq4.x;
      cs[0] += f3; cq[0] += f3 * f3;
      cs[1] += f4; cq[1] += f4 * f4;
      cs[2] += f5; cq[2] += f5 * f5;
      cs[3] += f6; cq[3] += f6 * f6;
      cs[4] += f7; cq[4] += f7 * f7;
      cs[5] += f8; cq[5] += f8 * f8;
      if (dr == 1) { center[0] = f4; center[1] = f5; center[2] = f6; center[3] = f7; }
    }
    // residual_ema for this row strip (float4 loads; hr re-read hits L2)
    const int gbase = (h0 + o) * WW + w0 + 4 * c4;
    float4 ha = *(const float4*)(hrb + gbase);
    float4 hb2 = *(const float4*)(hrb + gbase + HW);
    float4 hc = *(const float4*)(hrb + gbase + 2 * HW);
    float4 ea = *(const float4*)(eb + gbase);
    float4 eb2 = *(const float4*)(eb + gbase + HW);
    float4 ec = *(const float4*)(eb + gbase + 2 * HW);
    float e4[4];
    e4[0] = (fabsf(ha.x - ea.x) + fabsf(hb2.x - eb2.x) + fabsf(hc.x - ec.x)) / 255.0f;
    e4[1] = (fabsf(ha.y - ea.y) + fabsf(hb2.y - eb2.y) + fabsf(hc.y - ec.y)) / 255.0f;
    e4[2] = (fabsf(ha.z - ea.z) + fabsf(hb2.z - eb2.z) + fabsf(hc.z - ec.z)) / 255.0f;
    e4[3] = (fabsf(ha.w - ea.w) + fabsf(hb2.w - eb2.w) + fabsf(hc.w - ec.w)) / 255.0f;
#pragma unroll
    for (int cc = 0; cc < 4; ++cc) {
      float s = cs[cc] + cs[cc + 1] + cs[cc + 2];
      float q = cq[cc] + cq[cc + 1] + cq[cc + 2];
      float pvar = (q - s * s / 9.0f) / 8.0f;
      float rc = center[cc];
      v1 += rc;
      v2 += rc * rc;
      if (rc >= e4[cc]) v3 += pvar * (255.0f * rc);
    }
  }

  // block reduce (4 waves)
#pragma unroll
  for (int off = 32; off > 0; off >>= 1) {
    v1 += __shfl_down(v1, off, 64);
    v2 += __shfl_down(v2, off, 64);
    v3 += __shfl_down(v3, off, 64);
  }
  __shared__ float red[3][4];
  if (c4 == 0) {
    red[0][rs] = v1;
    red[1][rs] = v2;
    red[2][rs] = v3;
  }
  __syncthreads();
  if (tid == 0) {
    p_sum[bid] = red[0][0] + red[0][1] + red[0][2] + red[0][3];
    p_sum2[bid] = red[1][0] + red[1][1] + red[1][2] + red[1][3];
    p_loss[bid] = red[2][0] + red[2][1] + red[2][2] + red[2][3];
  }
}

// Single fused reduction: wave w handles batch w (128 partials each, 2/lane).
__global__ __launch_bounds__(1024) void wl1_reduce(
    const float* __restrict__ p_sum, const float* __restrict__ p_sum2,
    const float* __restrict__ p_loss, float* __restrict__ out) {
  const int tid = threadIdx.x;
  const int b = tid >> 6, k = tid & 63;
  const int i = b * TILES_PER_BATCH + k;
  double s = (double)p_sum[i] + (double)p_sum[i + 64];
  double s2 = (double)p_sum2[i] + (double)p_sum2[i + 64];
  double sl = (double)p_loss[i] + (double)p_loss[i + 64];
#pragma unroll
  for (int off = 32; off > 0; off >>= 1) {
    s += __shfl_down(s, off, 64);
    s2 += __shfl_down(s2, off, 64);
    sl += __shfl_down(sl, off, 64);
  }
  __shared__ double acc[BB];
  if (k == 0) {
    const double n = (double)HW;
    double var = (s2 - s * s / n) / (n - 1.0);
    acc[b] = pow(var, 0.2) * sl;
  }
  __syncthreads();
  if (tid == 0) {
    double tot = 0.0;
#pragma unroll
    for (int j = 0; j < BB; ++j) tot += acc[j];
    out[0] = (float)(tot / (double)((size_t)BB * CHW));
  }
}

extern "C" void kernel_launch(void* const* d_in, const int* in_sizes, int n_in,
                              void* d_out, int out_size, void* d_ws,
                              size_t ws_size, hipStream_t stream) {
  const float* sr = (const float*)d_in[0];
  const float* srema = (const float*)d_in[1];
  const float* hr = (const float*)d_in[2];
  float* out = (float*)d_out;

  float* p_sum = (float*)d_ws;
  float* p_sum2 = p_sum + NBLOCKS;
  float* p_loss = p_sum2 + NBLOCKS;

  wl1_main<<<NBLOCKS, 256, 0, stream>>>(sr, srema, hr, p_sum, p_sum2, p_loss);
  wl1_reduce<<<1, 1024, 0, stream>>>(p_sum, p_sum2, p_loss, out);
}